// Round 1
// baseline (250.567 us; speedup 1.0000x reference)
//
#include <hip/hip_runtime.h>

// B=2, S=2048, D=1024, H=16, hd=64, SCALE=32.
// softmax over batch axis (B=2) == pointwise sigmoid((s0-s1)/32); no k-normalization.

typedef _Float16 f16;
typedef __attribute__((ext_vector_type(8))) _Float16 f16x8;
typedef __attribute__((ext_vector_type(4))) _Float16 f16x4;
typedef __attribute__((ext_vector_type(4))) float f32x4;

#define MFMA16(a,b,c) __builtin_amdgcn_mfma_f32_16x16x32_f16(a,b,c,0,0,0)

// ---------------- x: fp32 -> fp16 ----------------
__global__ __launch_bounds__(256) void convert_x(const float* __restrict__ x,
                                                 f16* __restrict__ xh, int n4) {
    int i = blockIdx.x * 256 + threadIdx.x;
    if (i >= n4) return;
    float4 v = ((const float4*)x)[i];
    f16x4 h;
    h[0] = (f16)v.x; h[1] = (f16)v.y; h[2] = (f16)v.z; h[3] = (f16)v.w;
    *(f16x4*)(xh + (long)i * 4) = h;
}

// ---------------- weights: fp32 [1024][1024] -> fp16 transposed ----------------
__global__ __launch_bounds__(256) void transpose_w(const float* __restrict__ w0, const float* __restrict__ w1,
                                                   const float* __restrict__ w2, const float* __restrict__ w3,
                                                   f16* __restrict__ o0, f16* __restrict__ o1,
                                                   f16* __restrict__ o2, f16* __restrict__ o3) {
    const float* w; f16* o;
    switch (blockIdx.z) {
        case 0: w = w0; o = o0; break;
        case 1: w = w1; o = o1; break;
        case 2: w = w2; o = o2; break;
        default: w = w3; o = o3; break;
    }
    __shared__ alignas(16) f16 t[64][72];
    const int tid = threadIdx.x;
    const int d0 = blockIdx.x * 64, j0 = blockIdx.y * 64;
    #pragma unroll
    for (int it = 0; it < 4; ++it) {
        int idx = it * 256 + tid;            // 64 rows x 16 float4-chunks
        int row = idx >> 4, c4 = idx & 15;
        float4 v = *(const float4*)(w + (long)(d0 + row) * 1024 + j0 + c4 * 4);
        f16x4 h;
        h[0] = (f16)v.x; h[1] = (f16)v.y; h[2] = (f16)v.z; h[3] = (f16)v.w;
        *(f16x4*)&t[row][c4 * 4] = h;
    }
    __syncthreads();
    #pragma unroll
    for (int it = 0; it < 4; ++it) {
        int idx = it * 256 + tid;            // 64 out-rows (j) x 16 d4-chunks
        int jr = idx >> 4, d4 = idx & 15;
        f16x4 h;
        #pragma unroll
        for (int m = 0; m < 4; ++m) h[m] = t[d4 * 4 + m][jr];
        *(f16x4*)(o + (long)(j0 + jr) * 1024 + d0 + d4 * 4) = h;
    }
}

// ---------------- GEMM: C[4096x1024] = A[4096x1024] @ Bt^T, Bt row-major [n][k] ----------------
// MODE 1: fp16 out in Q/K layout [b][h][s][64]
// MODE 2: fp16 out in Vt layout [b][h][hd][s]
// MODE 3: fp32 out row-major [4096][1024]
template<int MODE>
__global__ __launch_bounds__(256, 1) void gemm_bt(const f16* __restrict__ A,
                                                  const f16* __restrict__ Bt,
                                                  void* __restrict__ outp) {
    __shared__ alignas(16) f16 As[128][72];
    __shared__ alignas(16) f16 Bs[128][72];
    const int tid = threadIdx.x;
    const int wave = tid >> 6, lane = tid & 63;
    const int l15 = lane & 15, lq = lane >> 4;
    const int m0 = blockIdx.x * 128, n0 = blockIdx.y * 128;
    const int wr = (wave >> 1) * 64, wc = (wave & 1) * 64;

    f32x4 acc[4][4] = {};

    for (int kt = 0; kt < 16; ++kt) {       // K = 1024, BK = 64
        __syncthreads();
        #pragma unroll
        for (int it = 0; it < 4; ++it) {
            int idx = it * 256 + tid;       // 128 rows x 8 16B-chunks per tensor
            int row = idx >> 3, c = idx & 7;
            *(f16x8*)&As[row][c * 8] = *(const f16x8*)(A  + (long)(m0 + row) * 1024 + kt * 64 + c * 8);
            *(f16x8*)&Bs[row][c * 8] = *(const f16x8*)(Bt + (long)(n0 + row) * 1024 + kt * 64 + c * 8);
        }
        __syncthreads();
        #pragma unroll
        for (int s2 = 0; s2 < 2; ++s2) {
            f16x8 af[4], bf[4];
            #pragma unroll
            for (int i = 0; i < 4; ++i) af[i] = *(const f16x8*)&As[wr + i * 16 + l15][s2 * 32 + lq * 8];
            #pragma unroll
            for (int j = 0; j < 4; ++j) bf[j] = *(const f16x8*)&Bs[wc + j * 16 + l15][s2 * 32 + lq * 8];
            #pragma unroll
            for (int i = 0; i < 4; ++i)
                #pragma unroll
                for (int j = 0; j < 4; ++j)
                    acc[i][j] = MFMA16(af[i], bf[j], acc[i][j]);
        }
    }

    #pragma unroll
    for (int i = 0; i < 4; ++i)
        #pragma unroll
        for (int j = 0; j < 4; ++j) {
            int gr0 = m0 + wr + i * 16 + lq * 4;   // + r gives global row (b*2048+s)
            int gc  = n0 + wc + j * 16 + l15;      // global col (h*64+hd)
            if (MODE == 2) {
                int b = gr0 >> 11, s = gr0 & 2047;
                int hh = gc >> 6, hd = gc & 63;
                f16x4 v;
                #pragma unroll
                for (int r = 0; r < 4; ++r) v[r] = (f16)acc[i][j][r];
                *(f16x4*)((f16*)outp + (long)((b * 16 + hh) * 64 + hd) * 2048 + s) = v;
            } else if (MODE == 1) {
                int hh = gc >> 6, hd = gc & 63;
                #pragma unroll
                for (int r = 0; r < 4; ++r) {
                    int gr = gr0 + r;
                    int b = gr >> 11, s = gr & 2047;
                    ((f16*)outp)[(long)((b * 16 + hh) * 2048 + s) * 64 + hd] = (f16)acc[i][j][r];
                }
            } else {
                #pragma unroll
                for (int r = 0; r < 4; ++r)
                    ((float*)outp)[(long)(gr0 + r) * 1024 + gc] = acc[i][j][r];
            }
        }
}

// ---------------- fused batch-coupled attention ----------------
// grid (16 q-tiles, 16 heads), 256 threads. Q frags in regs; K/Vt tiles in LDS;
// P = sigmoid((S0-S1)/32) routed through wave-private LDS (C-layout -> A-layout).
__global__ __launch_bounds__(256, 1) void attention_kernel(const f16* __restrict__ Qg,
                                                           const f16* __restrict__ Kg,
                                                           const f16* __restrict__ Vtg,
                                                           f16* __restrict__ vals) {
    __shared__ alignas(16) f16 Ks [2][64][72];
    __shared__ alignas(16) f16 Vts[2][64][72];
    __shared__ alignas(16) f16 Ps [4][32][72];
    const int tid = threadIdx.x;
    const int wave = tid >> 6, lane = tid & 63;
    const int l15 = lane & 15, lq = lane >> 4;
    const int h = blockIdx.y;
    const int q0 = blockIdx.x * 128;

    // preload Q fragments for this wave's 32 q-rows, both batches
    f16x8 qfr[2][2][2];   // [batch][q-frag][k-step]
    #pragma unroll
    for (int b = 0; b < 2; ++b)
        #pragma unroll
        for (int qq = 0; qq < 2; ++qq)
            #pragma unroll
            for (int s2 = 0; s2 < 2; ++s2)
                qfr[b][qq][s2] = *(const f16x8*)(Qg + (long)((b * 16 + h) * 2048 + q0 + wave * 32 + qq * 16 + l15) * 64
                                                 + s2 * 32 + lq * 8);

    f32x4 acc[2][2][4] = {};   // [batch][q-frag][hd-frag]

    for (int kt = 0; kt < 32; ++kt) {       // k-tiles of 64
        __syncthreads();
        #pragma unroll
        for (int it = 0; it < 4; ++it) {
            int idx = it * 256 + tid;       // 2b x 64 rows x 8 chunks = 1024
            int b = idx >> 9, row = (idx >> 3) & 63, c = idx & 7;
            *(f16x8*)&Ks [b][row][c * 8] = *(const f16x8*)(Kg  + (long)((b * 16 + h) * 2048 + kt * 64 + row) * 64 + c * 8);
            *(f16x8*)&Vts[b][row][c * 8] = *(const f16x8*)(Vtg + (long)((b * 16 + h) * 64 + row) * 2048 + kt * 64 + c * 8);
        }
        __syncthreads();

        // scores S[b][qq][kf] over 32q x 64k, inner hd=64
        f32x4 S[2][2][4] = {};
        #pragma unroll
        for (int b = 0; b < 2; ++b)
            #pragma unroll
            for (int s2 = 0; s2 < 2; ++s2) {
                f16x8 bf[4];
                #pragma unroll
                for (int kf = 0; kf < 4; ++kf)
                    bf[kf] = *(const f16x8*)&Ks[b][kf * 16 + l15][s2 * 32 + lq * 8];
                #pragma unroll
                for (int qq = 0; qq < 2; ++qq)
                    #pragma unroll
                    for (int kf = 0; kf < 4; ++kf)
                        S[b][qq][kf] = MFMA16(qfr[b][qq][s2], bf[kf], S[b][qq][kf]);
            }

        // p0 = sigmoid((s0-s1)/32) = 1/(1+exp2(-(s0-s1)*log2e/32))
        float p0[2][4][4];
        #pragma unroll
        for (int qq = 0; qq < 2; ++qq)
            #pragma unroll
            for (int kf = 0; kf < 4; ++kf)
                #pragma unroll
                for (int r = 0; r < 4; ++r) {
                    float d = (S[0][qq][kf][r] - S[1][qq][kf][r]) * 0.045084219f; // log2(e)/32
                    float e = __builtin_amdgcn_exp2f(-d);
                    p0[qq][kf][r] = __builtin_amdgcn_rcpf(1.0f + e);
                }

        // for each batch: write P (C-layout -> LDS row-major) then PV MFMA (A-layout reads)
        #pragma unroll
        for (int pb = 0; pb < 2; ++pb) {
            #pragma unroll
            for (int qq = 0; qq < 2; ++qq)
                #pragma unroll
                for (int kf = 0; kf < 4; ++kf)
                    #pragma unroll
                    for (int r = 0; r < 4; ++r) {
                        float p = pb ? (1.0f - p0[qq][kf][r]) : p0[qq][kf][r];
                        Ps[wave][qq * 16 + lq * 4 + r][kf * 16 + l15] = (f16)p;
                    }
            #pragma unroll
            for (int s2 = 0; s2 < 2; ++s2) {
                f16x8 pf[2], vf[4];
                #pragma unroll
                for (int qq = 0; qq < 2; ++qq)
                    pf[qq] = *(const f16x8*)&Ps[wave][qq * 16 + l15][s2 * 32 + lq * 8];
                #pragma unroll
                for (int hf = 0; hf < 4; ++hf)
                    vf[hf] = *(const f16x8*)&Vts[pb][hf * 16 + l15][s2 * 32 + lq * 8];
                #pragma unroll
                for (int qq = 0; qq < 2; ++qq)
                    #pragma unroll
                    for (int hf = 0; hf < 4; ++hf)
                        acc[pb][qq][hf] = MFMA16(pf[qq], vf[hf], acc[pb][qq][hf]);
            }
        }
    }

    // vals row-major [b*2048+s][1024] fp16
    #pragma unroll
    for (int b = 0; b < 2; ++b)
        #pragma unroll
        for (int qq = 0; qq < 2; ++qq)
            #pragma unroll
            for (int hf = 0; hf < 4; ++hf)
                #pragma unroll
                for (int r = 0; r < 4; ++r) {
                    int srow = q0 + wave * 32 + qq * 16 + lq * 4 + r;
                    vals[(long)(b * 2048 + srow) * 1024 + h * 64 + hf * 16 + l15] = (f16)acc[b][qq][hf][r];
                }
}

extern "C" void kernel_launch(void* const* d_in, const int* in_sizes, int n_in,
                              void* d_out, int out_size, void* d_ws, size_t ws_size,
                              hipStream_t stream) {
    const float* x  = (const float*)d_in[0];
    const float* wq = (const float*)d_in[1];
    const float* wk = (const float*)d_in[2];
    const float* wv = (const float*)d_in[3];
    const float* wo = (const float*)d_in[4];

    char* ws = (char*)d_ws;
    f16* xh   = (f16*)(ws);                    // 4096x1024 fp16        (8 MiB)
    f16* wqT  = (f16*)(ws + 8388608);          // 1024x1024 fp16 (w^T)  (2 MiB)
    f16* wkT  = (f16*)(ws + 10485760);
    f16* wvT  = (f16*)(ws + 12582912);
    f16* woT  = (f16*)(ws + 14680064);
    f16* Qg   = (f16*)(ws + 16777216);         // [2][16][2048][64] fp16 (8 MiB)
    f16* Kg   = (f16*)(ws + 25165824);
    f16* Vtg  = (f16*)(ws + 33554432);         // [2][16][64][2048] fp16
    f16* vals = (f16*)(ws + 41943040);         // 4096x1024 fp16
    (void)ws_size; (void)in_sizes; (void)n_in; (void)out_size;

    convert_x<<<4096, 256, 0, stream>>>(x, xh, (2 * 2048 * 1024) / 4);
    transpose_w<<<dim3(16, 16, 4), 256, 0, stream>>>(wq, wk, wv, wo, wqT, wkT, wvT, woT);

    gemm_bt<1><<<dim3(32, 8), 256, 0, stream>>>(xh, wqT, Qg);
    gemm_bt<1><<<dim3(32, 8), 256, 0, stream>>>(xh, wkT, Kg);
    gemm_bt<2><<<dim3(32, 8), 256, 0, stream>>>(xh, wvT, Vtg);

    attention_kernel<<<dim3(16, 16), 256, 0, stream>>>(Qg, Kg, Vtg, vals);

    gemm_bt<3><<<dim3(32, 8), 256, 0, stream>>>(vals, woT, d_out);
}

// Round 2
// 241.973 us; speedup vs baseline: 1.0355x; 1.0355x over previous
//
#include <hip/hip_runtime.h>

// B=2, S=2048, D=1024, H=16, hd=64, SCALE=32.
// softmax over batch axis (B=2) == pointwise sigmoid((s0-s1)/32); no k-normalization.

typedef _Float16 f16;
typedef __attribute__((ext_vector_type(8))) _Float16 f16x8;
typedef __attribute__((ext_vector_type(4))) _Float16 f16x4;
typedef __attribute__((ext_vector_type(4))) float f32x4;

#define MFMA16(a,b,c) __builtin_amdgcn_mfma_f32_16x16x32_f16(a,b,c,0,0,0)
// async global->LDS, 16B per lane; LDS dest = wave-uniform base + lane*16 (m104)
#define GLD16(gp, lp) __builtin_amdgcn_global_load_lds(                         \
    (const __attribute__((address_space(1))) void*)(gp),                        \
    (__attribute__((address_space(3))) void*)(lp), 16, 0, 0)

// ---------------- x: fp32 -> fp16 ----------------
__global__ __launch_bounds__(256) void convert_x(const float* __restrict__ x,
                                                 f16* __restrict__ xh, int n4) {
    int i = blockIdx.x * 256 + threadIdx.x;
    if (i >= n4) return;
    float4 v = ((const float4*)x)[i];
    f16x4 h;
    h[0] = (f16)v.x; h[1] = (f16)v.y; h[2] = (f16)v.z; h[3] = (f16)v.w;
    *(f16x4*)(xh + (long)i * 4) = h;
}

// ---------------- weights: fp32 [1024][1024] -> fp16 transposed ----------------
__global__ __launch_bounds__(256) void transpose_w(const float* __restrict__ w0, const float* __restrict__ w1,
                                                   const float* __restrict__ w2, const float* __restrict__ w3,
                                                   f16* __restrict__ o0, f16* __restrict__ o1,
                                                   f16* __restrict__ o2, f16* __restrict__ o3) {
    const float* w; f16* o;
    switch (blockIdx.z) {
        case 0: w = w0; o = o0; break;
        case 1: w = w1; o = o1; break;
        case 2: w = w2; o = o2; break;
        default: w = w3; o = o3; break;
    }
    __shared__ alignas(16) f16 t[64][72];
    const int tid = threadIdx.x;
    const int d0 = blockIdx.x * 64, j0 = blockIdx.y * 64;
    #pragma unroll
    for (int it = 0; it < 4; ++it) {
        int idx = it * 256 + tid;
        int row = idx >> 4, c4 = idx & 15;
        float4 v = *(const float4*)(w + (long)(d0 + row) * 1024 + j0 + c4 * 4);
        f16x4 h;
        h[0] = (f16)v.x; h[1] = (f16)v.y; h[2] = (f16)v.z; h[3] = (f16)v.w;
        *(f16x4*)&t[row][c4 * 4] = h;
    }
    __syncthreads();
    #pragma unroll
    for (int it = 0; it < 4; ++it) {
        int idx = it * 256 + tid;
        int jr = idx >> 4, d4 = idx & 15;
        f16x4 h;
        #pragma unroll
        for (int m = 0; m < 4; ++m) h[m] = t[d4 * 4 + m][jr];
        *(f16x4*)(o + (long)(j0 + jr) * 1024 + d0 + d4 * 4) = h;
    }
}

// ---------------- GEMM: C[4096x1024] = A @ Bt^T, Bt row-major [n][k] ----------------
// MODE 1: fp16 out [b][h][s][64]   MODE 2: fp16 out [b][h][hd][s] (Vt)   MODE 3: fp32 row-major
// ADDA: A = A0 + A1 elementwise (explicit staging); else global_load_lds staging.
template<int MODE, bool ADDA>
__global__ __launch_bounds__(256, 1) void gemm_bt(const f16* __restrict__ A0,
                                                  const f16* __restrict__ A1,
                                                  const f16* __restrict__ Bt,
                                                  void* __restrict__ outp) {
    constexpr int ASTR = ADDA ? 72 : 64;
    __shared__ alignas(16) f16 As[128][ASTR];
    __shared__ alignas(16) f16 Bs[128][64];
    const int tid = threadIdx.x;
    const int wave = tid >> 6, lane = tid & 63;
    const int l15 = lane & 15, lq = lane >> 4;
    const int m0 = blockIdx.x * 128, n0 = blockIdx.y * 128;
    const int wr = (wave >> 1) * 64, wc = (wave & 1) * 64;
    const int srow = wave * 32 + (lane >> 3), sch = (lane & 7) * 8;

    f32x4 acc[4][4] = {};

    for (int kt = 0; kt < 16; ++kt) {       // K = 1024, BK = 64
        __syncthreads();
        if (ADDA) {
            #pragma unroll
            for (int it = 0; it < 4; ++it) {
                int idx = it * 256 + tid;
                int row = idx >> 3, c = idx & 7;
                f16x8 a = *(const f16x8*)(A0 + (long)(m0 + row) * 1024 + kt * 64 + c * 8)
                        + *(const f16x8*)(A1 + (long)(m0 + row) * 1024 + kt * 64 + c * 8);
                *(f16x8*)&As[row][c * 8] = a;
            }
        } else {
            #pragma unroll
            for (int i = 0; i < 4; ++i) {
                GLD16(A0 + (long)(m0 + wave * 32 + i * 8 + (lane >> 3)) * 1024 + kt * 64 + sch,
                      &As[wave * 32 + i * 8][0]);
            }
        }
        #pragma unroll
        for (int i = 0; i < 4; ++i) {
            GLD16(Bt + (long)(n0 + wave * 32 + i * 8 + (lane >> 3)) * 1024 + kt * 64 + sch,
                  &Bs[wave * 32 + i * 8][0]);
        }
        __syncthreads();
        #pragma unroll
        for (int s2 = 0; s2 < 2; ++s2) {
            f16x8 af[4], bf[4];
            #pragma unroll
            for (int i = 0; i < 4; ++i) af[i] = *(const f16x8*)&As[wr + i * 16 + l15][s2 * 32 + lq * 8];
            #pragma unroll
            for (int j = 0; j < 4; ++j) bf[j] = *(const f16x8*)&Bs[wc + j * 16 + l15][s2 * 32 + lq * 8];
            #pragma unroll
            for (int i = 0; i < 4; ++i)
                #pragma unroll
                for (int j = 0; j < 4; ++j)
                    acc[i][j] = MFMA16(af[i], bf[j], acc[i][j]);
        }
    }

    #pragma unroll
    for (int i = 0; i < 4; ++i)
        #pragma unroll
        for (int j = 0; j < 4; ++j) {
            int gr0 = m0 + wr + i * 16 + lq * 4;   // + r -> global row (b*2048+s)
            int gc  = n0 + wc + j * 16 + l15;      // global col
            if (MODE == 2) {
                int b = gr0 >> 11, s = gr0 & 2047;
                int hh = gc >> 6, hd = gc & 63;
                f16x4 v;
                #pragma unroll
                for (int r = 0; r < 4; ++r) v[r] = (f16)acc[i][j][r];
                *(f16x4*)((f16*)outp + (long)((b * 16 + hh) * 64 + hd) * 2048 + s) = v;
            } else if (MODE == 1) {
                int hh = gc >> 6, hd = gc & 63;
                #pragma unroll
                for (int r = 0; r < 4; ++r) {
                    int gr = gr0 + r;
                    int b = gr >> 11, s = gr & 2047;
                    ((f16*)outp)[(long)((b * 16 + hh) * 2048 + s) * 64 + hd] = (f16)acc[i][j][r];
                }
            } else {
                #pragma unroll
                for (int r = 0; r < 4; ++r)
                    ((float*)outp)[(long)(gr0 + r) * 1024 + gc] = acc[i][j][r];
            }
        }
}

// ---------------- fused batch-coupled attention, split-k x2 ----------------
// 512 blocks: xcd-pinned head, 16 q-tiles of 128, ksplit 2. 4 waves; wave w -> q rows [w*32, w*32+32).
// S computed TRANSPOSED (MFMA(Kfrag, Qfrag)) so lane holds 4 contiguous k -> packed b64 P writes.
__global__ __launch_bounds__(256, 2) void attention_kernel(const f16* __restrict__ Qg,
                                                           const f16* __restrict__ Kg,
                                                           const f16* __restrict__ Vtg,
                                                           f16* __restrict__ vals0,
                                                           f16* __restrict__ vals1) {
    __shared__ alignas(16) f16 Ks [2][64][64];
    __shared__ alignas(16) f16 Vts[2][64][64];
    __shared__ alignas(16) f16 Ps [4][32][72];
    const int tid = threadIdx.x;
    const int wave = tid >> 6, lane = tid & 63;
    const int l15 = lane & 15, lq = lane >> 4;

    const int bid = blockIdx.x;
    const int xcd = bid & 7, sl = bid >> 3;          // sl 0..63
    const int h  = xcd * 2 + (sl & 1);               // head pinned to XCD -> K/V L2-resident
    const int qt = (sl >> 1) & 15, ks = sl >> 5;
    const int q0 = qt * 128, kt0 = ks * 16;
    f16* vals = ks ? vals1 : vals0;
    const int qr = q0 + wave * 32;

    // Q fragments in registers: [batch][qq][s2]
    f16x8 qfr[2][2][2];
    #pragma unroll
    for (int b2 = 0; b2 < 2; ++b2)
        #pragma unroll
        for (int qq = 0; qq < 2; ++qq)
            #pragma unroll
            for (int s2 = 0; s2 < 2; ++s2)
                qfr[b2][qq][s2] = *(const f16x8*)(Qg + (long)((b2 * 16 + h) * 2048 + qr + qq * 16 + l15) * 64
                                                  + s2 * 32 + lq * 8);

    f32x4 acc[2][2][4] = {};   // [batch][qq][hf]

    // staging roles: wave 0/1 -> K batch 0/1; wave 2/3 -> Vt batch 0/1
    const int tb = wave & 1;
    const f16* kbase = Kg  + (long)((tb * 16 + h) * 2048 + kt0 * 64) * 64 + lane * 8;
    const f16* vbase = Vtg + (long)((tb * 16 + h) * 64 + (lane >> 3)) * 2048 + kt0 * 64 + (lane & 7) * 8;

    for (int kt = 0; kt < 16; ++kt) {
        __syncthreads();
        if (wave < 2) {
            const f16* g = kbase + kt * 4096;       // 8 KB contiguous K tile
            f16* l = &Ks[tb][0][0];
            #pragma unroll
            for (int i = 0; i < 8; ++i) GLD16(g + i * 512, l + i * 512);
        } else {
            const f16* g = vbase + kt * 64;         // 64 rows of 128B, stride 4KB
            f16* l = &Vts[tb][0][0];
            #pragma unroll
            for (int i = 0; i < 8; ++i) GLD16(g + (long)i * 8 * 2048, l + i * 512);
        }
        __syncthreads();

        // S^T for both batches -> sigmoid -> packed P (f16x4 along contiguous k)
        f16x4 pp0[2][4], pp1[2][4];
        #pragma unroll
        for (int kf = 0; kf < 4; ++kf) {
            f32x4 S0[2] = {}, S1[2] = {};
            #pragma unroll
            for (int s2 = 0; s2 < 2; ++s2) {
                f16x8 a0 = *(const f16x8*)&Ks[0][kf * 16 + l15][s2 * 32 + lq * 8];
                f16x8 a1 = *(const f16x8*)&Ks[1][kf * 16 + l15][s2 * 32 + lq * 8];
                #pragma unroll
                for (int qq = 0; qq < 2; ++qq) {
                    S0[qq] = MFMA16(a0, qfr[0][qq][s2], S0[qq]);
                    S1[qq] = MFMA16(a1, qfr[1][qq][s2], S1[qq]);
                }
            }
            #pragma unroll
            for (int qq = 0; qq < 2; ++qq)
                #pragma unroll
                for (int r = 0; r < 4; ++r) {
                    float d = (S0[qq][r] - S1[qq][r]) * 0.045084219f;  // log2(e)/32
                    float p = __builtin_amdgcn_rcpf(1.0f + __builtin_amdgcn_exp2f(-d));
                    pp0[qq][kf][r] = (f16)p;
                    pp1[qq][kf][r] = (f16)(1.0f - p);
                }
        }

        #pragma unroll
        for (int pb = 0; pb < 2; ++pb) {
            #pragma unroll
            for (int qq = 0; qq < 2; ++qq)
                #pragma unroll
                for (int kf = 0; kf < 4; ++kf)
                    *(f16x4*)&Ps[wave][qq * 16 + l15][kf * 16 + lq * 4] = pb ? pp1[qq][kf] : pp0[qq][kf];
            #pragma unroll
            for (int s2 = 0; s2 < 2; ++s2) {
                f16x8 pf[2], vf[4];
                #pragma unroll
                for (int qq = 0; qq < 2; ++qq)
                    pf[qq] = *(const f16x8*)&Ps[wave][qq * 16 + l15][s2 * 32 + lq * 8];
                #pragma unroll
                for (int hf = 0; hf < 4; ++hf)
                    vf[hf] = *(const f16x8*)&Vts[pb][hf * 16 + l15][s2 * 32 + lq * 8];
                #pragma unroll
                for (int qq = 0; qq < 2; ++qq)
                    #pragma unroll
                    for (int hf = 0; hf < 4; ++hf)
                        acc[pb][qq][hf] = MFMA16(pf[qq], vf[hf], acc[pb][qq][hf]);
            }
        }
    }

    // partial vals, row-major [b*2048+s][1024] fp16
    #pragma unroll
    for (int b2 = 0; b2 < 2; ++b2)
        #pragma unroll
        for (int qq = 0; qq < 2; ++qq)
            #pragma unroll
            for (int hf = 0; hf < 4; ++hf)
                #pragma unroll
                for (int r = 0; r < 4; ++r)
                    vals[(long)(b2 * 2048 + qr + qq * 16 + lq * 4 + r) * 1024 + h * 64 + hf * 16 + l15]
                        = (f16)acc[b2][qq][hf][r];
}

extern "C" void kernel_launch(void* const* d_in, const int* in_sizes, int n_in,
                              void* d_out, int out_size, void* d_ws, size_t ws_size,
                              hipStream_t stream) {
    const float* x  = (const float*)d_in[0];
    const float* wq = (const float*)d_in[1];
    const float* wk = (const float*)d_in[2];
    const float* wv = (const float*)d_in[3];
    const float* wo = (const float*)d_in[4];

    char* ws = (char*)d_ws;
    f16* xh    = (f16*)(ws);                   // 8 MiB; dead after V gemm -> reused as vals0
    f16* wqT   = (f16*)(ws + 8388608);
    f16* wkT   = (f16*)(ws + 10485760);
    f16* wvT   = (f16*)(ws + 12582912);
    f16* woT   = (f16*)(ws + 14680064);
    f16* Qg    = (f16*)(ws + 16777216);        // [2][16][2048][64]
    f16* Kg    = (f16*)(ws + 25165824);
    f16* Vtg   = (f16*)(ws + 33554432);        // [2][16][64][2048]
    f16* vals1 = (f16*)(ws + 41943040);        // ksplit partial 1
    f16* vals0 = xh;                           // ksplit partial 0 (aliases dead xh)
    (void)ws_size; (void)in_sizes; (void)n_in; (void)out_size;

    convert_x<<<4096, 256, 0, stream>>>(x, xh, (2 * 2048 * 1024) / 4);
    transpose_w<<<dim3(16, 16, 4), 256, 0, stream>>>(wq, wk, wv, wo, wqT, wkT, wvT, woT);

    gemm_bt<1, false><<<dim3(32, 8), 256, 0, stream>>>(xh, nullptr, wqT, Qg);
    gemm_bt<1, false><<<dim3(32, 8), 256, 0, stream>>>(xh, nullptr, wkT, Kg);
    gemm_bt<2, false><<<dim3(32, 8), 256, 0, stream>>>(xh, nullptr, wvT, Vtg);

    attention_kernel<<<512, 256, 0, stream>>>(Qg, Kg, Vtg, vals0, vals1);

    gemm_bt<3, true><<<dim3(32, 8), 256, 0, stream>>>(vals0, vals1, woT, d_out);
}

// Round 4
// 217.971 us; speedup vs baseline: 1.1495x; 1.1101x over previous
//
#include <hip/hip_runtime.h>

// B=2, S=2048, D=1024, H=16, hd=64, SCALE=32.
// softmax over batch axis (B=2) == pointwise sigmoid((s0-s1)/32); no k-normalization.

typedef _Float16 f16;
typedef __attribute__((ext_vector_type(8))) _Float16 f16x8;
typedef __attribute__((ext_vector_type(4))) _Float16 f16x4;
typedef __attribute__((ext_vector_type(4))) float f32x4;

#define MFMA16(a,b,c) __builtin_amdgcn_mfma_f32_16x16x32_f16(a,b,c,0,0,0)
// async global->LDS, 16B per lane; LDS dest = wave-uniform base + lane*16 (m104)
#define GLD16(gp, lp) __builtin_amdgcn_global_load_lds(                         \
    (const __attribute__((address_space(1))) void*)(gp),                        \
    (__attribute__((address_space(3))) void*)(lp), 16, 0, 0)

// ---------------- x: fp32 -> fp16 ----------------
__global__ __launch_bounds__(256) void convert_x(const float* __restrict__ x,
                                                 f16* __restrict__ xh, int n4) {
    int i = blockIdx.x * 256 + threadIdx.x;
    if (i >= n4) return;
    float4 v = ((const float4*)x)[i];
    f16x4 h;
    h[0] = (f16)v.x; h[1] = (f16)v.y; h[2] = (f16)v.z; h[3] = (f16)v.w;
    *(f16x4*)(xh + (long)i * 4) = h;
}

// ---------------- weights: fp32 [1024][1024] -> fp16 transposed ----------------
__global__ __launch_bounds__(256) void transpose_w(const float* __restrict__ w0, const float* __restrict__ w1,
                                                   const float* __restrict__ w2, const float* __restrict__ w3,
                                                   f16* __restrict__ o0, f16* __restrict__ o1,
                                                   f16* __restrict__ o2, f16* __restrict__ o3) {
    const float* w; f16* o;
    switch (blockIdx.z) {
        case 0: w = w0; o = o0; break;
        case 1: w = w1; o = o1; break;
        case 2: w = w2; o = o2; break;
        default: w = w3; o = o3; break;
    }
    __shared__ alignas(16) f16 t[64][72];
    const int tid = threadIdx.x;
    const int d0 = blockIdx.x * 64, j0 = blockIdx.y * 64;
    #pragma unroll
    for (int it = 0; it < 4; ++it) {
        int idx = it * 256 + tid;
        int row = idx >> 4, c4 = idx & 15;
        float4 v = *(const float4*)(w + (long)(d0 + row) * 1024 + j0 + c4 * 4);
        f16x4 h;
        h[0] = (f16)v.x; h[1] = (f16)v.y; h[2] = (f16)v.z; h[3] = (f16)v.w;
        *(f16x4*)&t[row][c4 * 4] = h;
    }
    __syncthreads();
    #pragma unroll
    for (int it = 0; it < 4; ++it) {
        int idx = it * 256 + tid;
        int jr = idx >> 4, d4 = idx & 15;
        f16x4 h;
        #pragma unroll
        for (int m = 0; m < 4; ++m) h[m] = t[d4 * 4 + m][jr];
        *(f16x4*)(o + (long)(j0 + jr) * 1024 + d0 + d4 * 4) = h;
    }
}

// ---------------- fused QKV GEMM: [4096x1024] @ Wt^T, Wt = [wqT;wkT;wvT] [3072][1024] ----------------
// 128x128 tiles, grid(32,24) = 768 blocks = 3/CU. Epilogue layout per n-panel:
//   n0<1024 -> Qg [b][h][s][64]; n0<2048 -> Kg same; else Vtg [b][h][hd][s].
__global__ __launch_bounds__(256, 1) void gemm_qkv(const f16* __restrict__ A,
                                                   const f16* __restrict__ Wt,
                                                   f16* __restrict__ Qg,
                                                   f16* __restrict__ Kg,
                                                   f16* __restrict__ Vtg) {
    __shared__ alignas(16) f16 As[128][64];
    __shared__ alignas(16) f16 Bs[128][64];
    const int tid = threadIdx.x;
    const int wave = tid >> 6, lane = tid & 63;
    const int l15 = lane & 15, lq = lane >> 4;
    const int m0 = blockIdx.x * 128, n0 = blockIdx.y * 128;
    const int wr = (wave >> 1) * 64, wc = (wave & 1) * 64;
    const int r8 = lane >> 3, c8 = (lane & 7) * 8;

    f32x4 acc[4][4] = {};

    for (int kt = 0; kt < 16; ++kt) {       // K = 1024, BK = 64
        __syncthreads();
        #pragma unroll
        for (int i = 0; i < 4; ++i) {
            GLD16(A  + (long)(m0 + wave * 32 + i * 8 + r8) * 1024 + kt * 64 + c8, &As[wave * 32 + i * 8][0]);
            GLD16(Wt + (long)(n0 + wave * 32 + i * 8 + r8) * 1024 + kt * 64 + c8, &Bs[wave * 32 + i * 8][0]);
        }
        __syncthreads();
        #pragma unroll
        for (int s2 = 0; s2 < 2; ++s2) {
            f16x8 af[4], bf[4];
            #pragma unroll
            for (int i = 0; i < 4; ++i) af[i] = *(const f16x8*)&As[wr + i * 16 + l15][s2 * 32 + lq * 8];
            #pragma unroll
            for (int j = 0; j < 4; ++j) bf[j] = *(const f16x8*)&Bs[wc + j * 16 + l15][s2 * 32 + lq * 8];
            #pragma unroll
            for (int i = 0; i < 4; ++i)
                #pragma unroll
                for (int j = 0; j < 4; ++j)
                    acc[i][j] = MFMA16(af[i], bf[j], acc[i][j]);
        }
    }

    const int sel = n0 >> 10;                       // 0:Q 1:K 2:V (block-uniform)
    f16* dst = sel == 0 ? Qg : (sel == 1 ? Kg : Vtg);
    const int nb = n0 - (sel << 10);

    #pragma unroll
    for (int i = 0; i < 4; ++i)
        #pragma unroll
        for (int j = 0; j < 4; ++j) {
            int gr0 = m0 + wr + i * 16 + lq * 4;    // + r -> global row (b*2048+s)
            int gc  = nb + wc + j * 16 + l15;
            int hh = gc >> 6, hd = gc & 63;
            if (sel == 2) {
                int b = gr0 >> 11, s = gr0 & 2047;
                f16x4 v;
                #pragma unroll
                for (int r = 0; r < 4; ++r) v[r] = (f16)acc[i][j][r];
                *(f16x4*)(dst + (long)((b * 16 + hh) * 64 + hd) * 2048 + s) = v;
            } else {
                #pragma unroll
                for (int r = 0; r < 4; ++r) {
                    int gr = gr0 + r;
                    int b = gr >> 11, s = gr & 2047;
                    dst[(long)((b * 16 + hh) * 2048 + s) * 64 + hd] = (f16)acc[i][j][r];
                }
            }
        }
}

// ---------------- output GEMM: fp32 out = (vals0+vals1) @ woT^T ----------------
// BM=64, BN=128 -> grid(64,8) = 512 blocks = 2/CU. Waves 2x2, wave tile 32x64.
__global__ __launch_bounds__(256, 1) void gemm_out(const f16* __restrict__ A0,
                                                   const f16* __restrict__ A1,
                                                   const f16* __restrict__ Bt,
                                                   float* __restrict__ outp) {
    __shared__ alignas(16) f16 As[64][72];
    __shared__ alignas(16) f16 Bs[128][64];
    const int tid = threadIdx.x;
    const int wave = tid >> 6, lane = tid & 63;
    const int l15 = lane & 15, lq = lane >> 4;
    const int m0 = blockIdx.x * 64, n0 = blockIdx.y * 128;
    const int wr = (wave >> 1) * 32, wc = (wave & 1) * 64;
    const int r8 = lane >> 3, c8 = (lane & 7) * 8;

    f32x4 acc[2][4] = {};

    for (int kt = 0; kt < 16; ++kt) {
        __syncthreads();
        #pragma unroll
        for (int it = 0; it < 2; ++it) {            // A = A0+A1, 64x64, explicit staging
            int idx = it * 256 + tid;
            int row = idx >> 3, c = idx & 7;
            f16x8 a = *(const f16x8*)(A0 + (long)(m0 + row) * 1024 + kt * 64 + c * 8)
                    + *(const f16x8*)(A1 + (long)(m0 + row) * 1024 + kt * 64 + c * 8);
            *(f16x8*)&As[row][c * 8] = a;
        }
        #pragma unroll
        for (int i = 0; i < 4; ++i)
            GLD16(Bt + (long)(n0 + wave * 32 + i * 8 + r8) * 1024 + kt * 64 + c8, &Bs[wave * 32 + i * 8][0]);
        __syncthreads();
        #pragma unroll
        for (int s2 = 0; s2 < 2; ++s2) {
            f16x8 af[2], bf[4];
            #pragma unroll
            for (int i = 0; i < 2; ++i) af[i] = *(const f16x8*)&As[wr + i * 16 + l15][s2 * 32 + lq * 8];
            #pragma unroll
            for (int j = 0; j < 4; ++j) bf[j] = *(const f16x8*)&Bs[wc + j * 16 + l15][s2 * 32 + lq * 8];
            #pragma unroll
            for (int i = 0; i < 2; ++i)
                #pragma unroll
                for (int j = 0; j < 4; ++j)
                    acc[i][j] = MFMA16(af[i], bf[j], acc[i][j]);
        }
    }

    #pragma unroll
    for (int i = 0; i < 2; ++i)
        #pragma unroll
        for (int j = 0; j < 4; ++j) {
            int gr0 = m0 + wr + i * 16 + lq * 4;
            int gc  = n0 + wc + j * 16 + l15;
            #pragma unroll
            for (int r = 0; r < 4; ++r)
                outp[(long)(gr0 + r) * 1024 + gc] = acc[i][j][r];
        }
}

// ---------------- fused batch-coupled attention, split-k x2 (unchanged from R2) ----------------
__global__ __launch_bounds__(256, 2) void attention_kernel(const f16* __restrict__ Qg,
                                                           const f16* __restrict__ Kg,
                                                           const f16* __restrict__ Vtg,
                                                           f16* __restrict__ vals0,
                                                           f16* __restrict__ vals1) {
    __shared__ alignas(16) f16 Ks [2][64][64];
    __shared__ alignas(16) f16 Vts[2][64][64];
    __shared__ alignas(16) f16 Ps [4][32][72];
    const int tid = threadIdx.x;
    const int wave = tid >> 6, lane = tid & 63;
    const int l15 = lane & 15, lq = lane >> 4;

    const int bid = blockIdx.x;
    const int xcd = bid & 7, sl = bid >> 3;
    const int h  = xcd * 2 + (sl & 1);
    const int qt = (sl >> 1) & 15, ks = sl >> 5;
    const int q0 = qt * 128, kt0 = ks * 16;
    f16* vals = ks ? vals1 : vals0;
    const int qr = q0 + wave * 32;

    f16x8 qfr[2][2][2];
    #pragma unroll
    for (int b2 = 0; b2 < 2; ++b2)
        #pragma unroll
        for (int qq = 0; qq < 2; ++qq)
            #pragma unroll
            for (int s2 = 0; s2 < 2; ++s2)
                qfr[b2][qq][s2] = *(const f16x8*)(Qg + (long)((b2 * 16 + h) * 2048 + qr + qq * 16 + l15) * 64
                                                  + s2 * 32 + lq * 8);

    f32x4 acc[2][2][4] = {};

    const int tb = wave & 1;
    const f16* kbase = Kg  + (long)((tb * 16 + h) * 2048 + kt0 * 64) * 64 + lane * 8;
    const f16* vbase = Vtg + (long)((tb * 16 + h) * 64 + (lane >> 3)) * 2048 + kt0 * 64 + (lane & 7) * 8;

    for (int kt = 0; kt < 16; ++kt) {
        __syncthreads();
        if (wave < 2) {
            const f16* g = kbase + kt * 4096;
            f16* l = &Ks[tb][0][0];
            #pragma unroll
            for (int i = 0; i < 8; ++i) GLD16(g + i * 512, l + i * 512);
        } else {
            const f16* g = vbase + kt * 64;
            f16* l = &Vts[tb][0][0];
            #pragma unroll
            for (int i = 0; i < 8; ++i) GLD16(g + (long)i * 8 * 2048, l + i * 512);
        }
        __syncthreads();

        f16x4 pp0[2][4], pp1[2][4];
        #pragma unroll
        for (int kf = 0; kf < 4; ++kf) {
            f32x4 S0[2] = {}, S1[2] = {};
            #pragma unroll
            for (int s2 = 0; s2 < 2; ++s2) {
                f16x8 a0 = *(const f16x8*)&Ks[0][kf * 16 + l15][s2 * 32 + lq * 8];
                f16x8 a1 = *(const f16x8*)&Ks[1][kf * 16 + l15][s2 * 32 + lq * 8];
                #pragma unroll
                for (int qq = 0; qq < 2; ++qq) {
                    S0[qq] = MFMA16(a0, qfr[0][qq][s2], S0[qq]);
                    S1[qq] = MFMA16(a1, qfr[1][qq][s2], S1[qq]);
                }
            }
            #pragma unroll
            for (int qq = 0; qq < 2; ++qq)
                #pragma unroll
                for (int r = 0; r < 4; ++r) {
                    float d = (S0[qq][r] - S1[qq][r]) * 0.045084219f;  // log2(e)/32
                    float p = __builtin_amdgcn_rcpf(1.0f + __builtin_amdgcn_exp2f(-d));
                    pp0[qq][kf][r] = (f16)p;
                    pp1[qq][kf][r] = (f16)(1.0f - p);
                }
        }

        #pragma unroll
        for (int pb = 0; pb < 2; ++pb) {
            #pragma unroll
            for (int qq = 0; qq < 2; ++qq)
                #pragma unroll
                for (int kf = 0; kf < 4; ++kf)
                    *(f16x4*)&Ps[wave][qq * 16 + l15][kf * 16 + lq * 4] = pb ? pp1[qq][kf] : pp0[qq][kf];
            #pragma unroll
            for (int s2 = 0; s2 < 2; ++s2) {
                f16x8 pf[2], vf[4];
                #pragma unroll
                for (int qq = 0; qq < 2; ++qq)
                    pf[qq] = *(const f16x8*)&Ps[wave][qq * 16 + l15][s2 * 32 + lq * 8];
                #pragma unroll
                for (int hf = 0; hf < 4; ++hf)
                    vf[hf] = *(const f16x8*)&Vts[pb][hf * 16 + l15][s2 * 32 + lq * 8];
                #pragma unroll
                for (int qq = 0; qq < 2; ++qq)
                    #pragma unroll
                    for (int hf = 0; hf < 4; ++hf)
                        acc[pb][qq][hf] = MFMA16(pf[qq], vf[hf], acc[pb][qq][hf]);
            }
        }
    }

    #pragma unroll
    for (int b2 = 0; b2 < 2; ++b2)
        #pragma unroll
        for (int qq = 0; qq < 2; ++qq)
            #pragma unroll
            for (int hf = 0; hf < 4; ++hf)
                #pragma unroll
                for (int r = 0; r < 4; ++r)
                    vals[(long)(b2 * 2048 + qr + qq * 16 + lq * 4 + r) * 1024 + h * 64 + hf * 16 + l15]
                        = (f16)acc[b2][qq][hf][r];
}

extern "C" void kernel_launch(void* const* d_in, const int* in_sizes, int n_in,
                              void* d_out, int out_size, void* d_ws, size_t ws_size,
                              hipStream_t stream) {
    const float* x  = (const float*)d_in[0];
    const float* wq = (const float*)d_in[1];
    const float* wk = (const float*)d_in[2];
    const float* wv = (const float*)d_in[3];
    const float* wo = (const float*)d_in[4];

    char* ws = (char*)d_ws;
    f16* xh    = (f16*)(ws);                   // 8 MiB; dead after QKV gemm -> reused as vals0
    f16* wqT   = (f16*)(ws + 8388608);         // wqT,wkT,wvT contiguous = fused [3072][1024]
    f16* wkT   = (f16*)(ws + 10485760);
    f16* wvT   = (f16*)(ws + 12582912);
    f16* woT   = (f16*)(ws + 14680064);
    f16* Qg    = (f16*)(ws + 16777216);        // [2][16][2048][64]
    f16* Kg    = (f16*)(ws + 25165824);
    f16* Vtg   = (f16*)(ws + 33554432);        // [2][16][64][2048]
    f16* vals1 = (f16*)(ws + 41943040);
    f16* vals0 = xh;
    (void)ws_size; (void)in_sizes; (void)n_in; (void)out_size;

    convert_x<<<4096, 256, 0, stream>>>(x, xh, (2 * 2048 * 1024) / 4);
    transpose_w<<<dim3(16, 16, 4), 256, 0, stream>>>(wq, wk, wv, wo, wqT, wkT, wvT, woT);

    gemm_qkv<<<dim3(32, 24), 256, 0, stream>>>(xh, wqT, Qg, Kg, Vtg);

    attention_kernel<<<512, 256, 0, stream>>>(Qg, Kg, Vtg, vals0, vals1);

    gemm_out<<<dim3(64, 8), 256, 0, stream>>>(vals0, vals1, woT, (float*)d_out);
}

// Round 5
// 194.557 us; speedup vs baseline: 1.2879x; 1.1203x over previous
//
#include <hip/hip_runtime.h>

// B=2, S=2048, D=1024, H=16, hd=64, SCALE=32.
// softmax over batch axis (B=2) == pointwise sigmoid((s0-s1)/32); no k-normalization.
// LDS layout: unpadded 64-f16 rows (128B = 32 banks) with XOR chunk swizzle:
//   physical 16B-chunk = logical chunk ^ (row & 7)  -> conflict-free b128 phases.

typedef _Float16 f16;
typedef __attribute__((ext_vector_type(8))) _Float16 f16x8;
typedef __attribute__((ext_vector_type(4))) _Float16 f16x4;
typedef __attribute__((ext_vector_type(4))) float f32x4;

#define MFMA16(a,b,c) __builtin_amdgcn_mfma_f32_16x16x32_f16(a,b,c,0,0,0)
// async global->LDS, 16B per lane; LDS dest = wave-uniform base + lane*16 (m104)
#define GLD16(gp, lp) __builtin_amdgcn_global_load_lds(                         \
    (const __attribute__((address_space(1))) void*)(gp),                        \
    (__attribute__((address_space(3))) void*)(lp), 16, 0, 0)

// ---------------- x: fp32 -> fp16 ----------------
__global__ __launch_bounds__(256) void convert_x(const float* __restrict__ x,
                                                 f16* __restrict__ xh, int n4) {
    int i = blockIdx.x * 256 + threadIdx.x;
    if (i >= n4) return;
    float4 v = ((const float4*)x)[i];
    f16x4 h;
    h[0] = (f16)v.x; h[1] = (f16)v.y; h[2] = (f16)v.z; h[3] = (f16)v.w;
    *(f16x4*)(xh + (long)i * 4) = h;
}

// ---------------- weights: fp32 [1024][1024] -> fp16 transposed ----------------
__global__ __launch_bounds__(256) void transpose_w(const float* __restrict__ w0, const float* __restrict__ w1,
                                                   const float* __restrict__ w2, const float* __restrict__ w3,
                                                   f16* __restrict__ o0, f16* __restrict__ o1,
                                                   f16* __restrict__ o2, f16* __restrict__ o3) {
    const float* w; f16* o;
    switch (blockIdx.z) {
        case 0: w = w0; o = o0; break;
        case 1: w = w1; o = o1; break;
        case 2: w = w2; o = o2; break;
        default: w = w3; o = o3; break;
    }
    __shared__ alignas(16) f16 t[64][72];
    const int tid = threadIdx.x;
    const int d0 = blockIdx.x * 64, j0 = blockIdx.y * 64;
    #pragma unroll
    for (int it = 0; it < 4; ++it) {
        int idx = it * 256 + tid;
        int row = idx >> 4, c4 = idx & 15;
        float4 v = *(const float4*)(w + (long)(d0 + row) * 1024 + j0 + c4 * 4);
        f16x4 h;
        h[0] = (f16)v.x; h[1] = (f16)v.y; h[2] = (f16)v.z; h[3] = (f16)v.w;
        *(f16x4*)&t[row][c4 * 4] = h;
    }
    __syncthreads();
    #pragma unroll
    for (int it = 0; it < 4; ++it) {
        int idx = it * 256 + tid;
        int jr = idx >> 4, d4 = idx & 15;
        f16x4 h;
        #pragma unroll
        for (int m = 0; m < 4; ++m) h[m] = t[d4 * 4 + m][jr];
        *(f16x4*)(o + (long)(j0 + jr) * 1024 + d0 + d4 * 4) = h;
    }
}

// ---------------- fused QKV GEMM: [4096x1024] @ Wt^T, Wt = [wqT;wkT;wvT] [3072][1024] ----------------
// 128x128 tiles, grid(32,24) = 768 blocks = 3/CU.
__global__ __launch_bounds__(256, 1) void gemm_qkv(const f16* __restrict__ A,
                                                   const f16* __restrict__ Wt,
                                                   f16* __restrict__ Qg,
                                                   f16* __restrict__ Kg,
                                                   f16* __restrict__ Vtg) {
    __shared__ alignas(16) f16 As[128][64];
    __shared__ alignas(16) f16 Bs[128][64];
    const int tid = threadIdx.x;
    const int wave = tid >> 6, lane = tid & 63;
    const int l15 = lane & 15, lq = lane >> 4;
    const int sw = l15 & 7;                          // reader row&7
    const int m0 = blockIdx.x * 128, n0 = blockIdx.y * 128;
    const int wr = (wave >> 1) * 64, wc = (wave & 1) * 64;
    const int r8 = lane >> 3;
    const int swc8 = ((lane & 7) ^ r8) * 8;          // staged global chunk = chunk ^ row&7

    f32x4 acc[4][4] = {};

    for (int kt = 0; kt < 16; ++kt) {       // K = 1024, BK = 64
        __syncthreads();
        #pragma unroll
        for (int i = 0; i < 4; ++i) {
            GLD16(A  + (long)(m0 + wave * 32 + i * 8 + r8) * 1024 + kt * 64 + swc8, &As[wave * 32 + i * 8][0]);
            GLD16(Wt + (long)(n0 + wave * 32 + i * 8 + r8) * 1024 + kt * 64 + swc8, &Bs[wave * 32 + i * 8][0]);
        }
        __syncthreads();
        #pragma unroll
        for (int s2 = 0; s2 < 2; ++s2) {
            const int rc = ((s2 * 4 + lq) ^ sw) << 3;
            f16x8 af[4], bf[4];
            #pragma unroll
            for (int i = 0; i < 4; ++i) af[i] = *(const f16x8*)&As[wr + i * 16 + l15][rc];
            #pragma unroll
            for (int j = 0; j < 4; ++j) bf[j] = *(const f16x8*)&Bs[wc + j * 16 + l15][rc];
            #pragma unroll
            for (int i = 0; i < 4; ++i)
                #pragma unroll
                for (int j = 0; j < 4; ++j)
                    acc[i][j] = MFMA16(af[i], bf[j], acc[i][j]);
        }
    }

    const int sel = n0 >> 10;                       // 0:Q 1:K 2:V (block-uniform)
    f16* dst = sel == 0 ? Qg : (sel == 1 ? Kg : Vtg);
    const int nb = n0 - (sel << 10);

    #pragma unroll
    for (int i = 0; i < 4; ++i)
        #pragma unroll
        for (int j = 0; j < 4; ++j) {
            int gr0 = m0 + wr + i * 16 + lq * 4;    // + r -> global row (b*2048+s)
            int gc  = nb + wc + j * 16 + l15;
            int hh = gc >> 6, hd = gc & 63;
            if (sel == 2) {
                int b = gr0 >> 11, s = gr0 & 2047;
                f16x4 v;
                #pragma unroll
                for (int r = 0; r < 4; ++r) v[r] = (f16)acc[i][j][r];
                *(f16x4*)(dst + (long)((b * 16 + hh) * 64 + hd) * 2048 + s) = v;
            } else {
                #pragma unroll
                for (int r = 0; r < 4; ++r) {
                    int gr = gr0 + r;
                    int b = gr >> 11, s = gr & 2047;
                    dst[(long)((b * 16 + hh) * 2048 + s) * 64 + hd] = (f16)acc[i][j][r];
                }
            }
        }
}

// ---------------- output GEMM: fp32 out = (vals0+vals1) @ woT^T ----------------
// BM=64, BN=128 -> grid(64,8) = 512 blocks = 2/CU.
__global__ __launch_bounds__(256, 1) void gemm_out(const f16* __restrict__ A0,
                                                   const f16* __restrict__ A1,
                                                   const f16* __restrict__ Bt,
                                                   float* __restrict__ outp) {
    __shared__ alignas(16) f16 As[64][72];          // padded: verified conflict-free pattern
    __shared__ alignas(16) f16 Bs[128][64];         // unpadded + swizzle
    const int tid = threadIdx.x;
    const int wave = tid >> 6, lane = tid & 63;
    const int l15 = lane & 15, lq = lane >> 4;
    const int sw = l15 & 7;
    const int m0 = blockIdx.x * 64, n0 = blockIdx.y * 128;
    const int wr = (wave >> 1) * 32, wc = (wave & 1) * 64;
    const int r8 = lane >> 3;
    const int swc8 = ((lane & 7) ^ r8) * 8;

    f32x4 acc[2][4] = {};

    for (int kt = 0; kt < 16; ++kt) {
        __syncthreads();
        #pragma unroll
        for (int it = 0; it < 2; ++it) {            // A = A0+A1, 64x64, explicit staging
            int idx = it * 256 + tid;
            int row = idx >> 3, c = idx & 7;
            f16x8 a = *(const f16x8*)(A0 + (long)(m0 + row) * 1024 + kt * 64 + c * 8)
                    + *(const f16x8*)(A1 + (long)(m0 + row) * 1024 + kt * 64 + c * 8);
            *(f16x8*)&As[row][c * 8] = a;
        }
        #pragma unroll
        for (int i = 0; i < 4; ++i)
            GLD16(Bt + (long)(n0 + wave * 32 + i * 8 + r8) * 1024 + kt * 64 + swc8, &Bs[wave * 32 + i * 8][0]);
        __syncthreads();
        #pragma unroll
        for (int s2 = 0; s2 < 2; ++s2) {
            const int rc = ((s2 * 4 + lq) ^ sw) << 3;
            f16x8 af[2], bf[4];
            #pragma unroll
            for (int i = 0; i < 2; ++i) af[i] = *(const f16x8*)&As[wr + i * 16 + l15][s2 * 32 + lq * 8];
            #pragma unroll
            for (int j = 0; j < 4; ++j) bf[j] = *(const f16x8*)&Bs[wc + j * 16 + l15][rc];
            #pragma unroll
            for (int i = 0; i < 2; ++i)
                #pragma unroll
                for (int j = 0; j < 4; ++j)
                    acc[i][j] = MFMA16(af[i], bf[j], acc[i][j]);
        }
    }

    #pragma unroll
    for (int i = 0; i < 2; ++i)
        #pragma unroll
        for (int j = 0; j < 4; ++j) {
            int gr0 = m0 + wr + i * 16 + lq * 4;
            int gc  = n0 + wc + j * 16 + l15;
            #pragma unroll
            for (int r = 0; r < 4; ++r)
                outp[(long)(gr0 + r) * 1024 + gc] = acc[i][j][r];
        }
}

// ---------------- fused batch-coupled attention, split-k x2, swizzled LDS ----------------
__global__ __launch_bounds__(256, 2) void attention_kernel(const f16* __restrict__ Qg,
                                                           const f16* __restrict__ Kg,
                                                           const f16* __restrict__ Vtg,
                                                           f16* __restrict__ vals0,
                                                           f16* __restrict__ vals1) {
    __shared__ alignas(16) f16 Ks [2][64][64];
    __shared__ alignas(16) f16 Vts[2][64][64];
    __shared__ alignas(16) f16 Ps [4][32][64];
    const int tid = threadIdx.x;
    const int wave = tid >> 6, lane = tid & 63;
    const int l15 = lane & 15, lq = lane >> 4;
    const int sw = l15 & 7;

    const int bid = blockIdx.x;
    const int xcd = bid & 7, sl = bid >> 3;
    const int h  = xcd * 2 + (sl & 1);               // head pinned to XCD
    const int qt = (sl >> 1) & 15, ks = sl >> 5;
    const int q0 = qt * 128, kt0 = ks * 16;
    f16* vals = ks ? vals1 : vals0;
    const int qr = q0 + wave * 32;

    f16x8 qfr[2][2][2];
    #pragma unroll
    for (int b2 = 0; b2 < 2; ++b2)
        #pragma unroll
        for (int qq = 0; qq < 2; ++qq)
            #pragma unroll
            for (int s2 = 0; s2 < 2; ++s2)
                qfr[b2][qq][s2] = *(const f16x8*)(Qg + (long)((b2 * 16 + h) * 2048 + qr + qq * 16 + l15) * 64
                                                  + s2 * 32 + lq * 8);

    f32x4 acc[2][2][4] = {};

    const int tb = wave & 1;
    const int r8 = lane >> 3;
    const int swc8 = ((lane & 7) ^ r8) * 8;          // swizzled source chunk for staging
    const f16* kbase = Kg  + (long)((tb * 16 + h) * 2048 + kt0 * 64) * 64 + r8 * 64 + swc8;
    const f16* vbase = Vtg + (long)((tb * 16 + h) * 64 + r8) * 2048 + kt0 * 64 + swc8;

    for (int kt = 0; kt < 16; ++kt) {
        __syncthreads();
        if (wave < 2) {
            const f16* g = kbase + kt * 4096;
            f16* l = &Ks[tb][0][0];
            #pragma unroll
            for (int i = 0; i < 8; ++i) GLD16(g + i * 512, l + i * 512);
        } else {
            const f16* g = vbase + kt * 64;
            f16* l = &Vts[tb][0][0];
            #pragma unroll
            for (int i = 0; i < 8; ++i) GLD16(g + (long)i * 8 * 2048, l + i * 512);
        }
        __syncthreads();

        f16x4 pp0[2][4], pp1[2][4];
        #pragma unroll
        for (int kf = 0; kf < 4; ++kf) {
            f32x4 S0[2] = {}, S1[2] = {};
            #pragma unroll
            for (int s2 = 0; s2 < 2; ++s2) {
                const int rc = ((s2 * 4 + lq) ^ sw) << 3;
                f16x8 a0 = *(const f16x8*)&Ks[0][kf * 16 + l15][rc];
                f16x8 a1 = *(const f16x8*)&Ks[1][kf * 16 + l15][rc];
                #pragma unroll
                for (int qq = 0; qq < 2; ++qq) {
                    S0[qq] = MFMA16(a0, qfr[0][qq][s2], S0[qq]);
                    S1[qq] = MFMA16(a1, qfr[1][qq][s2], S1[qq]);
                }
            }
            #pragma unroll
            for (int qq = 0; qq < 2; ++qq)
                #pragma unroll
                for (int r = 0; r < 4; ++r) {
                    float d = (S0[qq][r] - S1[qq][r]) * 0.045084219f;  // log2(e)/32
                    float p = __builtin_amdgcn_rcpf(1.0f + __builtin_amdgcn_exp2f(-d));
                    pp0[qq][kf][r] = (f16)p;
                    pp1[qq][kf][r] = (f16)(1.0f - p);
                }
        }

        // P write: logical col = kf*16+lq*4 -> chunk 2kf+(lq>>1), sub (lq&1)*4; row&7 = l15&7
        const int pwsub = (lq & 1) << 2;
        #pragma unroll
        for (int pb = 0; pb < 2; ++pb) {
            #pragma unroll
            for (int qq = 0; qq < 2; ++qq)
                #pragma unroll
                for (int kf = 0; kf < 4; ++kf)
                    *(f16x4*)&Ps[wave][qq * 16 + l15][(((2 * kf + (lq >> 1)) ^ sw) << 3) + pwsub]
                        = pb ? pp1[qq][kf] : pp0[qq][kf];
            #pragma unroll
            for (int s2 = 0; s2 < 2; ++s2) {
                const int rc = ((s2 * 4 + lq) ^ sw) << 3;
                f16x8 pf[2], vf[4];
                #pragma unroll
                for (int qq = 0; qq < 2; ++qq)
                    pf[qq] = *(const f16x8*)&Ps[wave][qq * 16 + l15][rc];
                #pragma unroll
                for (int hf = 0; hf < 4; ++hf)
                    vf[hf] = *(const f16x8*)&Vts[pb][hf * 16 + l15][rc];
                #pragma unroll
                for (int qq = 0; qq < 2; ++qq)
                    #pragma unroll
                    for (int hf = 0; hf < 4; ++hf)
                        acc[pb][qq][hf] = MFMA16(pf[qq], vf[hf], acc[pb][qq][hf]);
            }
        }
    }

    #pragma unroll
    for (int b2 = 0; b2 < 2; ++b2)
        #pragma unroll
        for (int qq = 0; qq < 2; ++qq)
            #pragma unroll
            for (int hf = 0; hf < 4; ++hf)
                #pragma unroll
                for (int r = 0; r < 4; ++r)
                    vals[(long)(b2 * 2048 + qr + qq * 16 + lq * 4 + r) * 1024 + h * 64 + hf * 16 + l15]
                        = (f16)acc[b2][qq][hf][r];
}

extern "C" void kernel_launch(void* const* d_in, const int* in_sizes, int n_in,
                              void* d_out, int out_size, void* d_ws, size_t ws_size,
                              hipStream_t stream) {
    const float* x  = (const float*)d_in[0];
    const float* wq = (const float*)d_in[1];
    const float* wk = (const float*)d_in[2];
    const float* wv = (const float*)d_in[3];
    const float* wo = (const float*)d_in[4];

    char* ws = (char*)d_ws;
    f16* xh    = (f16*)(ws);                   // 8 MiB; dead after QKV gemm -> reused as vals0
    f16* wqT   = (f16*)(ws + 8388608);         // wqT,wkT,wvT contiguous = fused [3072][1024]
    f16* wkT   = (f16*)(ws + 10485760);
    f16* wvT   = (f16*)(ws + 12582912);
    f16* woT   = (f16*)(ws + 14680064);
    f16* Qg    = (f16*)(ws + 16777216);        // [2][16][2048][64]
    f16* Kg    = (f16*)(ws + 25165824);
    f16* Vtg   = (f16*)(ws + 33554432);        // [2][16][64][2048]
    f16* vals1 = (f16*)(ws + 41943040);
    f16* vals0 = xh;
    (void)ws_size; (void)in_sizes; (void)n_in; (void)out_size;

    convert_x<<<4096, 256, 0, stream>>>(x, xh, (2 * 2048 * 1024) / 4);
    transpose_w<<<dim3(16, 16, 4), 256, 0, stream>>>(wq, wk, wv, wo, wqT, wkT, wvT, woT);

    gemm_qkv<<<dim3(32, 24), 256, 0, stream>>>(xh, wqT, Qg, Kg, Vtg);

    attention_kernel<<<512, 256, 0, stream>>>(Qg, Kg, Vtg, vals0, vals1);

    gemm_out<<<dim3(64, 8), 256, 0, stream>>>(vals0, vals1, woT, (float*)d_out);
}